// Round 3
// baseline (236.830 us; speedup 1.0000x reference)
//
#include <hip/hip_runtime.h>
#include <math.h>

#define NB 256
#define TPB 256
#define EPS 1e-5f
#define LOG2E 1.4426950408889634f

// ws float offsets
#define WS_CNT 0
#define WS_GEN 1
#define WS_A 16      // 4 floats
#define WS_PART 64   // 12 arrays of 256 floats (SoA): [0..3]=m2, [4..7]=se, [8..11]=sd
#define WS_Z 4096    // 4 x 256 floats: z0,z1,z2,z3

__device__ __forceinline__ float gelu_fast(float v) {
    float u = 0.7978845608028654f * (v + 0.044715f * v * v * v);
    float e = __expf(2.0f * u);          // tanh(u) = 1 - 2/(e^{2u}+1); saturates safely
    return 0.5f * v * (2.0f - 2.0f / (e + 1.0f));
}

// sense-reversing grid barrier; cnt/gen zeroed by vf_init each call.
__device__ __forceinline__ void grid_barrier(unsigned* cnt, unsigned* gen, unsigned nb) {
    __syncthreads();
    __threadfence();  // release: push this block's stores to device scope
    if (threadIdx.x == 0) {
        unsigned g0 = __hip_atomic_load(gen, __ATOMIC_RELAXED, __HIP_MEMORY_SCOPE_AGENT);
        unsigned old = __hip_atomic_fetch_add(cnt, 1u, __ATOMIC_RELAXED, __HIP_MEMORY_SCOPE_AGENT);
        if (old == nb - 1u) {
            __hip_atomic_store(cnt, 0u, __ATOMIC_RELAXED, __HIP_MEMORY_SCOPE_AGENT);
            __hip_atomic_store(gen, g0 + 1u, __ATOMIC_RELEASE, __HIP_MEMORY_SCOPE_AGENT);
        } else {
            while (__hip_atomic_load(gen, __ATOMIC_RELAXED, __HIP_MEMORY_SCOPE_AGENT) == g0)
                __builtin_amdgcn_s_sleep(2);
        }
    }
    __syncthreads();
    __threadfence();  // acquire: invalidate stale cached lines before reading others' data
}

__device__ __forceinline__ float block_sum_all(float v, float* sc, int lane, int wave) {
    for (int o = 32; o; o >>= 1) v += __shfl_xor(v, o);
    __syncthreads();
    if (lane == 0) sc[wave] = v;
    __syncthreads();
    return sc[0] + sc[1] + sc[2] + sc[3];
}

// 1 block x 256: A_h = sum_d Wk[h*64+d]*(Wq*t+bq)[h*64+d]; zero barrier state.
__global__ void vf_init(const float* __restrict__ t, const float* __restrict__ Wq,
                        const float* __restrict__ bq, const float* __restrict__ Wk,
                        float* __restrict__ wsf) {
    int i = threadIdx.x;
    float q = Wq[i] * t[0] + bq[i];
    float prod = Wk[i] * q;
    for (int o = 32; o; o >>= 1) prod += __shfl_xor(prod, o);
    if ((i & 63) == 0) wsf[WS_A + (i >> 6)] = prod;  // one wave per head
    if (i == 0) {
        ((unsigned*)wsf)[WS_CNT] = 0u;
        ((unsigned*)wsf)[WS_GEN] = 0u;
    }
}

__global__ __launch_bounds__(TPB, 1) void vf_fused(
    const float* __restrict__ x, const float* __restrict__ t,
    const float* __restrict__ Wv, const float* __restrict__ bv,
    const float* __restrict__ W0, const float* __restrict__ b0,
    const float* __restrict__ Wh, const float* __restrict__ bh,
    const float* __restrict__ Wout, const float* __restrict__ bout,
    const float* __restrict__ g, float* __restrict__ out, float* __restrict__ wsf) {

    __shared__ float xs[3072];
    __shared__ float hs[TPB];
    __shared__ float sc[32];
    unsigned* cnt = (unsigned*)wsf + WS_CNT;
    unsigned* gen = (unsigned*)wsf + WS_GEN;
    const int tid = threadIdx.x;
    const int bid = blockIdx.x;
    const int lane = tid & 63, wave = tid >> 6;

    // ---- prefetch call-invariant weights into registers (latency hidden under phase 1) ----
    float w1 = Wh[bid * 256 + tid];
    float w2 = Wh[65536 + bid * 256 + tid];
    float w3 = Wh[131072 + bid * 256 + tid];
    float gg0 = g[tid], gg1 = g[256 + tid], gg2 = g[512 + tid], gg3 = g[768 + tid];
    float bz1 = bh[bid], bz2 = bh[256 + bid], bz3 = bh[512 + bid];
    float b0v = b0[bid];
    float t0 = t[0];
    float wvv = (tid < 64) ? Wv[tid] : 0.f;
    float bvv = (tid < 64) ? bv[tid] : 0.f;

    for (int i = tid; i < 3072; i += TPB) xs[i] = x[i];
    __syncthreads();

    // ---- phase 1: pairs (single sweep, distances kept in registers) ----
    float c2[4];
    #pragma unroll
    for (int h = 0; h < 4; ++h) c2[h] = wsf[WS_A + h] * LOG2E;

    int gi = (bid * TPB + tid) * 16;       // 65536 threads * 16 = 1024^2 ordered pairs
    int i0 = gi >> 10, j0 = gi & 1023;     // 16 | 1024 -> row fixed per thread
    float xi0 = xs[3 * i0], xi1 = xs[3 * i0 + 1], xi2 = xs[3 * i0 + 2];
    float dreg[16];
    float tmax = -INFINITY, tmin = INFINITY;
    #pragma unroll
    for (int e = 0; e < 16; ++e) {
        int j = j0 + e;
        float dx = xi0 - xs[3 * j], dy = xi1 - xs[3 * j + 1], dz = xi2 - xs[3 * j + 2];
        float d = sqrtf(dx * dx + dy * dy + dz * dz);
        dreg[e] = d;
        if (j != i0) { tmax = fmaxf(tmax, d); tmin = fminf(tmin, d); }
    }
    for (int o = 32; o; o >>= 1) {
        tmax = fmaxf(tmax, __shfl_xor(tmax, o));
        tmin = fminf(tmin, __shfl_xor(tmin, o));
    }
    if (lane == 0) { sc[wave] = tmax; sc[8 + wave] = tmin; }
    __syncthreads();
    float bmax = fmaxf(fmaxf(sc[0], sc[1]), fmaxf(sc[2], sc[3]));
    float bmin = fminf(fminf(sc[8], sc[9]), fminf(sc[10], sc[11]));
    float m2[4];  // block-local max logit (exp2 domain); logits monotone in d
    #pragma unroll
    for (int h = 0; h < 4; ++h) m2[h] = (c2[h] >= 0.f) ? c2[h] * bmax : c2[h] * bmin;

    float se[4] = {0, 0, 0, 0}, sd[4] = {0, 0, 0, 0};
    #pragma unroll
    for (int e = 0; e < 16; ++e) {
        int j = j0 + e;
        if (j == i0) continue;
        float d = dreg[e];
        #pragma unroll
        for (int h = 0; h < 4; ++h) {
            float ee = exp2f(c2[h] * d - m2[h]);
            se[h] += ee;
            sd[h] += d * ee;
        }
    }
    for (int o = 32; o; o >>= 1) {
        #pragma unroll
        for (int h = 0; h < 4; ++h) { se[h] += __shfl_xor(se[h], o); sd[h] += __shfl_xor(sd[h], o); }
    }
    __syncthreads();
    if (lane == 0) {
        #pragma unroll
        for (int h = 0; h < 4; ++h) { sc[wave * 8 + h] = se[h]; sc[wave * 8 + 4 + h] = sd[h]; }
    }
    __syncthreads();
    if (tid < 4) wsf[WS_PART + tid * 256 + bid] = m2[tid];
    if (tid < 8) wsf[WS_PART + (4 + tid) * 256 + bid] = sc[tid] + sc[8 + tid] + sc[16 + tid] + sc[24 + tid];

    // prefetch this block's W0 row while others finish phase 1
    float w0r[13];
    #pragma unroll
    for (int k = 0; k < 12; ++k) w0r[k] = W0[bid * 3137 + tid + k * 256];
    w0r[12] = (tid < 65) ? W0[bid * 3137 + 3072 + tid] : 0.f;

    grid_barrier(cnt, gen, NB);

    // ---- phase 2: LSE-merge 256 partials (redundant per block) + layer0 matvec ----
    float pm[4], pse[4], psd[4];
    #pragma unroll
    for (int h = 0; h < 4; ++h) {
        pm[h]  = wsf[WS_PART + h * 256 + tid];
        pse[h] = wsf[WS_PART + (4 + h) * 256 + tid];
        psd[h] = wsf[WS_PART + (8 + h) * 256 + tid];
    }
    float pmr[4] = {pm[0], pm[1], pm[2], pm[3]};
    for (int o = 32; o; o >>= 1) {
        #pragma unroll
        for (int h = 0; h < 4; ++h) pmr[h] = fmaxf(pmr[h], __shfl_xor(pmr[h], o));
    }
    if (lane == 0) {
        #pragma unroll
        for (int h = 0; h < 4; ++h) sc[wave * 4 + h] = pmr[h];
    }
    __syncthreads();
    float gm[4];
    #pragma unroll
    for (int h = 0; h < 4; ++h)
        gm[h] = fmaxf(fmaxf(sc[h], sc[4 + h]), fmaxf(sc[8 + h], sc[12 + h]));
    float s8[8];
    #pragma unroll
    for (int h = 0; h < 4; ++h) {
        float scl = exp2f(pm[h] - gm[h]);
        s8[h] = pse[h] * scl;
        s8[4 + h] = psd[h] * scl;
    }
    for (int o = 32; o; o >>= 1) {
        #pragma unroll
        for (int k = 0; k < 8; ++k) s8[k] += __shfl_xor(s8[k], o);
    }
    __syncthreads();
    if (lane == 0) {
        #pragma unroll
        for (int k = 0; k < 8; ++k) sc[wave * 8 + k] = s8[k];
    }
    __syncthreads();
    float s_tot = 0.f;
    #pragma unroll
    for (int h = 0; h < 4; ++h) {
        float seh = sc[h] + sc[8 + h] + sc[16 + h] + sc[24 + h];
        float sdh = sc[4 + h] + sc[12 + h] + sc[20 + h] + sc[28 + h];
        s_tot += sdh / seh;
    }

    // layer0: z0[bid] = W0[bid,:] . [x, s_tot*Wv+4bv, t] + b0[bid]
    float acc = 0.f;
    #pragma unroll
    for (int k = 0; k < 12; ++k) acc += w0r[k] * xs[tid + k * 256];
    float feat12 = (tid < 64) ? (s_tot * wvv + 4.0f * bvv) : ((tid == 64) ? t0 : 0.f);
    acc += w0r[12] * feat12;
    for (int o = 32; o; o >>= 1) acc += __shfl_xor(acc, o);
    __syncthreads();
    if (lane == 0) sc[wave] = acc;
    __syncthreads();
    if (tid == 0) wsf[WS_Z + bid] = sc[0] + sc[1] + sc[2] + sc[3] + b0v;

    grid_barrier(cnt, gen, NB);

    // ---- hidden layers: thread t holds W[bid][t] and h[t] -> dot is a block reduce ----
    {
        float zv = wsf[WS_Z + tid];
        float ssum = block_sum_all(zv * zv, sc, lane, wave);
        float hv = gelu_fast(zv * rsqrtf(ssum * (1.f / 256.f) + EPS) * gg0);
        float a = w1 * hv;
        for (int o = 32; o; o >>= 1) a += __shfl_xor(a, o);
        __syncthreads();
        if (lane == 0) sc[wave] = a;
        __syncthreads();
        if (tid == 0) wsf[WS_Z + 256 + bid] = sc[0] + sc[1] + sc[2] + sc[3] + bz1;
    }
    grid_barrier(cnt, gen, NB);
    {
        float zv = wsf[WS_Z + 256 + tid];
        float ssum = block_sum_all(zv * zv, sc, lane, wave);
        float hv = gelu_fast(zv * rsqrtf(ssum * (1.f / 256.f) + EPS) * gg1);
        float a = w2 * hv;
        for (int o = 32; o; o >>= 1) a += __shfl_xor(a, o);
        __syncthreads();
        if (lane == 0) sc[wave] = a;
        __syncthreads();
        if (tid == 0) wsf[WS_Z + 512 + bid] = sc[0] + sc[1] + sc[2] + sc[3] + bz2;
    }
    grid_barrier(cnt, gen, NB);
    {
        float zv = wsf[WS_Z + 512 + tid];
        float ssum = block_sum_all(zv * zv, sc, lane, wave);
        float hv = gelu_fast(zv * rsqrtf(ssum * (1.f / 256.f) + EPS) * gg2);
        float a = w3 * hv;
        for (int o = 32; o; o >>= 1) a += __shfl_xor(a, o);
        __syncthreads();
        if (lane == 0) sc[wave] = a;
        __syncthreads();
        if (tid == 0) wsf[WS_Z + 768 + bid] = sc[0] + sc[1] + sc[2] + sc[3] + bz3;
    }
    grid_barrier(cnt, gen, NB);

    // ---- output layer: 12 rows per block, 3 rows per wave ----
    {
        float zv = wsf[WS_Z + 768 + tid];
        float ssum = block_sum_all(zv * zv, sc, lane, wave);
        float hv = gelu_fast(zv * rsqrtf(ssum * (1.f / 256.f) + EPS) * gg3);
        hs[tid] = hv;
        __syncthreads();
        #pragma unroll
        for (int k = 0; k < 3; ++k) {
            int r = bid * 12 + wave * 3 + k;
            const float* row = Wout + r * 256;
            float a = 0.f;
            #pragma unroll
            for (int q = 0; q < 4; ++q) a += row[lane + 64 * q] * hs[lane + 64 * q];
            for (int o = 32; o; o >>= 1) a += __shfl_xor(a, o);
            if (lane == 0) out[r] = a + bout[r];
        }
    }
}

extern "C" void kernel_launch(void* const* d_in, const int* in_sizes, int n_in,
                              void* d_out, int out_size, void* d_ws, size_t ws_size,
                              hipStream_t stream) {
    const float* x = (const float*)d_in[0];
    const float* t = (const float*)d_in[1];
    const float* Wk = (const float*)d_in[2];
    // d_in[3] = bk: cancels in softmax, unused
    const float* Wv = (const float*)d_in[4];
    const float* bv = (const float*)d_in[5];
    const float* Wq = (const float*)d_in[6];
    const float* bq = (const float*)d_in[7];
    const float* W0 = (const float*)d_in[8];
    const float* b0 = (const float*)d_in[9];
    const float* Wh = (const float*)d_in[10];
    const float* bh = (const float*)d_in[11];
    const float* Wout = (const float*)d_in[12];
    const float* bout = (const float*)d_in[13];
    const float* g = (const float*)d_in[14];
    float* out = (float*)d_out;
    float* wsf = (float*)d_ws;

    vf_init<<<1, 256, 0, stream>>>(t, Wq, bq, Wk, wsf);
    vf_fused<<<NB, TPB, 0, stream>>>(x, t, Wv, bv, W0, b0, Wh, bh, Wout, bout, g, out, wsf);
}

// Round 4
// 43.231 us; speedup vs baseline: 5.4782x; 5.4782x over previous
//
#include <hip/hip_runtime.h>
#include <math.h>

#define NB 256
#define TPB 256
#define EPS 1e-5f
#define LOG2E 1.4426950408889634f

// ws layout
// uints  [0 .. 319]  : 5 one-shot barriers, stride 64 uints (cnt at +0, flag at +32)
// floats [384 .. 387]: A_h (4)
// floats [512 ..3583]: partials, 12 SoA arrays of 256: [0..3]=m2 [4..7]=se [8..11]=sd
// floats [4096..5119]: z0,z1,z2,z3 (4 x 256)
#define WS_A 384
#define WS_PART 512
#define WS_Z 4096

__device__ __forceinline__ float gelu_fast(float v) {
    float u = 0.7978845608028654f * (v + 0.044715f * v * v * v);
    float e = __expf(2.0f * u);          // tanh(u) = 1 - 2/(e^{2u}+1); saturates safely
    return 0.5f * v * (2.0f - 2.0f / (e + 1.0f));
}

// coherent-point (LLC) data exchange: sc1 atomics, no cache-maintenance fences
__device__ __forceinline__ void st_coh(float* p, float v) {
    __hip_atomic_store(p, v, __ATOMIC_RELAXED, __HIP_MEMORY_SCOPE_AGENT);
}
__device__ __forceinline__ float ld_coh(const float* p) {
    return __hip_atomic_load(p, __ATOMIC_RELAXED, __HIP_MEMORY_SCOPE_AGENT);
}

// one-shot grid barrier: __syncthreads drains vmcnt (sc1 stores visible at LLC),
// then one fetch_add per block; last block raises flag; no threadfence anywhere.
__device__ __forceinline__ void grid_barrier(unsigned* slot, unsigned nb) {
    asm volatile("s_waitcnt vmcnt(0)" ::: "memory");
    __syncthreads();
    if (threadIdx.x == 0) {
        unsigned old = __hip_atomic_fetch_add(slot, 1u, __ATOMIC_RELAXED, __HIP_MEMORY_SCOPE_AGENT);
        if (old == nb - 1u) {
            __hip_atomic_store(slot + 32, 1u, __ATOMIC_RELAXED, __HIP_MEMORY_SCOPE_AGENT);
        } else {
            while (__hip_atomic_load(slot + 32, __ATOMIC_RELAXED, __HIP_MEMORY_SCOPE_AGENT) == 0u)
                __builtin_amdgcn_s_sleep(1);
        }
    }
    __syncthreads();
}

__device__ __forceinline__ float block_sum_all(float v, float* sc, int lane, int wave) {
    for (int o = 32; o; o >>= 1) v += __shfl_xor(v, o);
    __syncthreads();
    if (lane == 0) sc[wave] = v;
    __syncthreads();
    return sc[0] + sc[1] + sc[2] + sc[3];
}

// 1 block x 256: A_h = sum_d Wk[h*64+d]*(Wq*t+bq)[h*64+d]; zero the 5 barrier slots.
__global__ void vf_init(const float* __restrict__ t, const float* __restrict__ Wq,
                        const float* __restrict__ bq, const float* __restrict__ Wk,
                        float* __restrict__ wsf) {
    int i = threadIdx.x;
    for (int k = i; k < 320; k += 256) ((unsigned*)wsf)[k] = 0u;
    float q = Wq[i] * t[0] + bq[i];
    float prod = Wk[i] * q;
    for (int o = 32; o; o >>= 1) prod += __shfl_xor(prod, o);
    if ((i & 63) == 0) wsf[WS_A + (i >> 6)] = prod;  // one wave per head
}

__global__ __launch_bounds__(TPB, 1) void vf_fused(
    const float* __restrict__ x, const float* __restrict__ t,
    const float* __restrict__ Wv, const float* __restrict__ bv,
    const float* __restrict__ W0, const float* __restrict__ b0,
    const float* __restrict__ Wh, const float* __restrict__ bh,
    const float* __restrict__ Wout, const float* __restrict__ bout,
    const float* __restrict__ g, float* __restrict__ out, float* __restrict__ wsf) {

    __shared__ float xs[3072];
    __shared__ float hs[TPB];
    __shared__ float sc[32];
    unsigned* bar = (unsigned*)wsf;
    const int tid = threadIdx.x;
    const int bid = blockIdx.x;
    const int lane = tid & 63, wave = tid >> 6;

    // ---- prefetch call-invariant weights into registers (latency hidden under phase 1) ----
    float w1 = Wh[bid * 256 + tid];
    float w2 = Wh[65536 + bid * 256 + tid];
    float w3 = Wh[131072 + bid * 256 + tid];
    float gg0 = g[tid], gg1 = g[256 + tid], gg2 = g[512 + tid], gg3 = g[768 + tid];
    float bz1 = bh[bid], bz2 = bh[256 + bid], bz3 = bh[512 + bid];
    float b0v = b0[bid];
    float t0 = t[0];
    float wvv = (tid < 64) ? Wv[tid] : 0.f;
    float bvv = (tid < 64) ? bv[tid] : 0.f;

    for (int i = tid; i < 3072; i += TPB) xs[i] = x[i];
    __syncthreads();

    // ---- phase 1: pairs (single sweep, distances kept in registers) ----
    float c2[4];
    #pragma unroll
    for (int h = 0; h < 4; ++h) c2[h] = wsf[WS_A + h] * LOG2E;

    int gi = (bid * TPB + tid) * 16;       // 65536 threads * 16 = 1024^2 ordered pairs
    int i0 = gi >> 10, j0 = gi & 1023;     // 16 | 1024 -> row fixed per thread
    float xi0 = xs[3 * i0], xi1 = xs[3 * i0 + 1], xi2 = xs[3 * i0 + 2];
    float dreg[16];
    float tmax = -INFINITY, tmin = INFINITY;
    #pragma unroll
    for (int e = 0; e < 16; ++e) {
        int j = j0 + e;
        float dx = xi0 - xs[3 * j], dy = xi1 - xs[3 * j + 1], dz = xi2 - xs[3 * j + 2];
        float d = sqrtf(dx * dx + dy * dy + dz * dz);
        dreg[e] = d;
        if (j != i0) { tmax = fmaxf(tmax, d); tmin = fminf(tmin, d); }
    }
    for (int o = 32; o; o >>= 1) {
        tmax = fmaxf(tmax, __shfl_xor(tmax, o));
        tmin = fminf(tmin, __shfl_xor(tmin, o));
    }
    if (lane == 0) { sc[wave] = tmax; sc[8 + wave] = tmin; }
    __syncthreads();
    float bmax = fmaxf(fmaxf(sc[0], sc[1]), fmaxf(sc[2], sc[3]));
    float bmin = fminf(fminf(sc[8], sc[9]), fminf(sc[10], sc[11]));
    float m2[4];  // block-local max logit (exp2 domain); logits monotone in d
    #pragma unroll
    for (int h = 0; h < 4; ++h) m2[h] = (c2[h] >= 0.f) ? c2[h] * bmax : c2[h] * bmin;

    float se[4] = {0, 0, 0, 0}, sd[4] = {0, 0, 0, 0};
    #pragma unroll
    for (int e = 0; e < 16; ++e) {
        int j = j0 + e;
        if (j == i0) continue;
        float d = dreg[e];
        #pragma unroll
        for (int h = 0; h < 4; ++h) {
            float ee = exp2f(c2[h] * d - m2[h]);
            se[h] += ee;
            sd[h] += d * ee;
        }
    }
    for (int o = 32; o; o >>= 1) {
        #pragma unroll
        for (int h = 0; h < 4; ++h) { se[h] += __shfl_xor(se[h], o); sd[h] += __shfl_xor(sd[h], o); }
    }
    __syncthreads();
    if (lane == 0) {
        #pragma unroll
        for (int h = 0; h < 4; ++h) { sc[wave * 8 + h] = se[h]; sc[wave * 8 + 4 + h] = sd[h]; }
    }
    __syncthreads();
    if (tid < 4) st_coh(&wsf[WS_PART + tid * 256 + bid], m2[tid]);
    if (tid < 8) st_coh(&wsf[WS_PART + (4 + tid) * 256 + bid],
                        sc[tid] + sc[8 + tid] + sc[16 + tid] + sc[24 + tid]);

    // prefetch this block's W0 row while others finish phase 1
    float w0r[13];
    #pragma unroll
    for (int k = 0; k < 12; ++k) w0r[k] = W0[bid * 3137 + tid + k * 256];
    w0r[12] = (tid < 65) ? W0[bid * 3137 + 3072 + tid] : 0.f;

    grid_barrier(bar + 0 * 64, NB);

    // ---- phase 2: LSE-merge 256 partials (redundant per block) + layer0 matvec ----
    float pm[4], pse[4], psd[4];
    #pragma unroll
    for (int h = 0; h < 4; ++h) {
        pm[h]  = ld_coh(&wsf[WS_PART + h * 256 + tid]);
        pse[h] = ld_coh(&wsf[WS_PART + (4 + h) * 256 + tid]);
        psd[h] = ld_coh(&wsf[WS_PART + (8 + h) * 256 + tid]);
    }
    float pmr[4] = {pm[0], pm[1], pm[2], pm[3]};
    for (int o = 32; o; o >>= 1) {
        #pragma unroll
        for (int h = 0; h < 4; ++h) pmr[h] = fmaxf(pmr[h], __shfl_xor(pmr[h], o));
    }
    if (lane == 0) {
        #pragma unroll
        for (int h = 0; h < 4; ++h) sc[wave * 4 + h] = pmr[h];
    }
    __syncthreads();
    float gm[4];
    #pragma unroll
    for (int h = 0; h < 4; ++h)
        gm[h] = fmaxf(fmaxf(sc[h], sc[4 + h]), fmaxf(sc[8 + h], sc[12 + h]));
    float s8[8];
    #pragma unroll
    for (int h = 0; h < 4; ++h) {
        float scl = exp2f(pm[h] - gm[h]);
        s8[h] = pse[h] * scl;
        s8[4 + h] = psd[h] * scl;
    }
    for (int o = 32; o; o >>= 1) {
        #pragma unroll
        for (int k = 0; k < 8; ++k) s8[k] += __shfl_xor(s8[k], o);
    }
    __syncthreads();
    if (lane == 0) {
        #pragma unroll
        for (int k = 0; k < 8; ++k) sc[wave * 8 + k] = s8[k];
    }
    __syncthreads();
    float s_tot = 0.f;
    #pragma unroll
    for (int h = 0; h < 4; ++h) {
        float seh = sc[h] + sc[8 + h] + sc[16 + h] + sc[24 + h];
        float sdh = sc[4 + h] + sc[12 + h] + sc[20 + h] + sc[28 + h];
        s_tot += sdh / seh;
    }

    // layer0: z0[bid] = W0[bid,:] . [x, s_tot*Wv+4bv, t] + b0[bid]
    float acc = 0.f;
    #pragma unroll
    for (int k = 0; k < 12; ++k) acc += w0r[k] * xs[tid + k * 256];
    float feat12 = (tid < 64) ? (s_tot * wvv + 4.0f * bvv) : ((tid == 64) ? t0 : 0.f);
    acc += w0r[12] * feat12;
    for (int o = 32; o; o >>= 1) acc += __shfl_xor(acc, o);
    __syncthreads();
    if (lane == 0) sc[wave] = acc;
    __syncthreads();
    if (tid == 0) st_coh(&wsf[WS_Z + bid], sc[0] + sc[1] + sc[2] + sc[3] + b0v);

    grid_barrier(bar + 1 * 64, NB);

    // ---- hidden layers: thread t holds W[bid][t] and h[t] -> dot is a block reduce ----
    {
        float zv = ld_coh(&wsf[WS_Z + tid]);
        float ssum = block_sum_all(zv * zv, sc, lane, wave);
        float hv = gelu_fast(zv * rsqrtf(ssum * (1.f / 256.f) + EPS) * gg0);
        float a = w1 * hv;
        for (int o = 32; o; o >>= 1) a += __shfl_xor(a, o);
        __syncthreads();
        if (lane == 0) sc[wave] = a;
        __syncthreads();
        if (tid == 0) st_coh(&wsf[WS_Z + 256 + bid], sc[0] + sc[1] + sc[2] + sc[3] + bz1);
    }
    grid_barrier(bar + 2 * 64, NB);
    {
        float zv = ld_coh(&wsf[WS_Z + 256 + tid]);
        float ssum = block_sum_all(zv * zv, sc, lane, wave);
        float hv = gelu_fast(zv * rsqrtf(ssum * (1.f / 256.f) + EPS) * gg1);
        float a = w2 * hv;
        for (int o = 32; o; o >>= 1) a += __shfl_xor(a, o);
        __syncthreads();
        if (lane == 0) sc[wave] = a;
        __syncthreads();
        if (tid == 0) st_coh(&wsf[WS_Z + 512 + bid], sc[0] + sc[1] + sc[2] + sc[3] + bz2);
    }
    grid_barrier(bar + 3 * 64, NB);
    {
        float zv = ld_coh(&wsf[WS_Z + 512 + tid]);
        float ssum = block_sum_all(zv * zv, sc, lane, wave);
        float hv = gelu_fast(zv * rsqrtf(ssum * (1.f / 256.f) + EPS) * gg2);
        float a = w3 * hv;
        for (int o = 32; o; o >>= 1) a += __shfl_xor(a, o);
        __syncthreads();
        if (lane == 0) sc[wave] = a;
        __syncthreads();
        if (tid == 0) st_coh(&wsf[WS_Z + 768 + bid], sc[0] + sc[1] + sc[2] + sc[3] + bz3);
    }
    grid_barrier(bar + 4 * 64, NB);

    // ---- output layer: 12 rows per block, 3 rows per wave ----
    {
        float zv = ld_coh(&wsf[WS_Z + 768 + tid]);
        float ssum = block_sum_all(zv * zv, sc, lane, wave);
        float hv = gelu_fast(zv * rsqrtf(ssum * (1.f / 256.f) + EPS) * gg3);
        hs[tid] = hv;
        __syncthreads();
        #pragma unroll
        for (int k = 0; k < 3; ++k) {
            int r = bid * 12 + wave * 3 + k;
            const float* row = Wout + r * 256;
            float a = 0.f;
            #pragma unroll
            for (int q = 0; q < 4; ++q) a += row[lane + 64 * q] * hs[lane + 64 * q];
            for (int o = 32; o; o >>= 1) a += __shfl_xor(a, o);
            if (lane == 0) out[r] = a + bout[r];
        }
    }
}

extern "C" void kernel_launch(void* const* d_in, const int* in_sizes, int n_in,
                              void* d_out, int out_size, void* d_ws, size_t ws_size,
                              hipStream_t stream) {
    const float* x = (const float*)d_in[0];
    const float* t = (const float*)d_in[1];
    const float* Wk = (const float*)d_in[2];
    // d_in[3] = bk: cancels in softmax, unused
    const float* Wv = (const float*)d_in[4];
    const float* bv = (const float*)d_in[5];
    const float* Wq = (const float*)d_in[6];
    const float* bq = (const float*)d_in[7];
    const float* W0 = (const float*)d_in[8];
    const float* b0 = (const float*)d_in[9];
    const float* Wh = (const float*)d_in[10];
    const float* bh = (const float*)d_in[11];
    const float* Wout = (const float*)d_in[12];
    const float* bout = (const float*)d_in[13];
    const float* g = (const float*)d_in[14];
    float* out = (float*)d_out;
    float* wsf = (float*)d_ws;

    vf_init<<<1, 256, 0, stream>>>(t, Wq, bq, Wk, wsf);
    vf_fused<<<NB, TPB, 0, stream>>>(x, t, Wv, bv, W0, b0, Wh, bh, Wout, bout, g, out, wsf);
}

// Round 5
// 33.283 us; speedup vs baseline: 7.1157x; 1.2989x over previous
//
#include <hip/hip_runtime.h>
#include <math.h>

#define NB 256
#define TPB 256
#define EPS 1e-5f
#define LOG2E 1.4426950408889634f

// ws layout (uint/float indices into 4-byte words)
// uints [0 .. 15359]: 5 tree barriers, 3072 uints (12KB) each:
//   leaves at +k*64 (k=0..15), root at +16*64, flag copies at +(32+k)*64
// floats [15872..15875]: A_h (4)
// floats [16384..19455]: partials, 12 SoA arrays of 256: [0..3]=m2 [4..7]=se [8..11]=sd
// floats [20480..21503]: z0,z1,z2,z3 (4 x 256)
#define BAR_REGION 3072
#define WS_A 15872
#define WS_PART 16384
#define WS_Z 20480

__device__ __forceinline__ float gelu_fast(float v) {
    float u = 0.7978845608028654f * (v + 0.044715f * v * v * v);
    float e = __expf(2.0f * u);          // tanh(u) = 1 - 2/(e^{2u}+1); saturates safely
    return 0.5f * v * (2.0f - 2.0f / (e + 1.0f));
}

// coherent-point (LLC) data exchange: sc1 atomics, no cache-maintenance fences
__device__ __forceinline__ void st_coh(float* p, float v) {
    __hip_atomic_store(p, v, __ATOMIC_RELAXED, __HIP_MEMORY_SCOPE_AGENT);
}
__device__ __forceinline__ float ld_coh(const float* p) {
    return __hip_atomic_load(p, __ATOMIC_RELAXED, __HIP_MEMORY_SCOPE_AGENT);
}

// one-shot TREE grid barrier: 16 leaves x 16 blocks -> root -> 16 flag copies.
// __syncthreads + vmcnt(0) drains this block's sc1 stores to the coherence
// point before arrival; flag poll gates the next phase's reads.
__device__ __forceinline__ void grid_barrier(unsigned* base, int bid) {
    asm volatile("s_waitcnt vmcnt(0)" ::: "memory");
    __syncthreads();
    if (threadIdx.x == 0) {
        unsigned leaf = (unsigned)bid & 15u;
        unsigned old = __hip_atomic_fetch_add(base + leaf * 64, 1u,
                                              __ATOMIC_RELAXED, __HIP_MEMORY_SCOPE_AGENT);
        if (old == 15u) {
            unsigned rold = __hip_atomic_fetch_add(base + 16 * 64, 1u,
                                                   __ATOMIC_RELAXED, __HIP_MEMORY_SCOPE_AGENT);
            if (rold == 15u) {
                #pragma unroll
                for (int k = 0; k < 16; ++k)
                    __hip_atomic_store(base + (32 + k) * 64, 1u,
                                       __ATOMIC_RELAXED, __HIP_MEMORY_SCOPE_AGENT);
            }
        }
        unsigned* flagp = base + (32 + leaf) * 64;
        while (__hip_atomic_load(flagp, __ATOMIC_RELAXED, __HIP_MEMORY_SCOPE_AGENT) == 0u)
            __builtin_amdgcn_s_sleep(2);
    }
    __syncthreads();
}

__device__ __forceinline__ float block_sum_all(float v, float* sc, int lane, int wave) {
    for (int o = 32; o; o >>= 1) v += __shfl_xor(v, o);
    __syncthreads();
    if (lane == 0) sc[wave] = v;
    __syncthreads();
    return sc[0] + sc[1] + sc[2] + sc[3];
}

// 1 block x 256: A_h = sum_d Wk[h*64+d]*(Wq*t+bq)[h*64+d]; zero 5 barrier regions.
__global__ void vf_init(const float* __restrict__ t, const float* __restrict__ Wq,
                        const float* __restrict__ bq, const float* __restrict__ Wk,
                        float* __restrict__ wsf) {
    int i = threadIdx.x;
    for (int k = i; k < 5 * BAR_REGION; k += 256) ((unsigned*)wsf)[k] = 0u;
    float q = Wq[i] * t[0] + bq[i];
    float prod = Wk[i] * q;
    for (int o = 32; o; o >>= 1) prod += __shfl_xor(prod, o);
    if ((i & 63) == 0) wsf[WS_A + (i >> 6)] = prod;  // one wave per head
}

__global__ __launch_bounds__(TPB, 1) void vf_fused(
    const float* __restrict__ x, const float* __restrict__ t,
    const float* __restrict__ Wv, const float* __restrict__ bv,
    const float* __restrict__ W0, const float* __restrict__ b0,
    const float* __restrict__ Wh, const float* __restrict__ bh,
    const float* __restrict__ Wout, const float* __restrict__ bout,
    const float* __restrict__ g, float* __restrict__ out, float* __restrict__ wsf) {

    __shared__ float xs[3072];
    __shared__ float hs[TPB];
    __shared__ float sc[32];
    unsigned* bar = (unsigned*)wsf;
    const int tid = threadIdx.x;
    const int bid = blockIdx.x;
    const int lane = tid & 63, wave = tid >> 6;

    // ---- prefetch ALL call-invariant weights into registers ----
    float w1 = Wh[bid * 256 + tid];
    float w2 = Wh[65536 + bid * 256 + tid];
    float w3 = Wh[131072 + bid * 256 + tid];
    float gg0 = g[tid], gg1 = g[256 + tid], gg2 = g[512 + tid], gg3 = g[768 + tid];
    float bz1 = bh[bid], bz2 = bh[256 + bid], bz3 = bh[512 + bid];
    float b0v = b0[bid];
    float t0 = t[0];
    float wvv = (tid < 64) ? Wv[tid] : 0.f;
    float bvv = (tid < 64) ? bv[tid] : 0.f;
    // output layer: rows bid*12 + wave*3 + k, element lane + 64*q
    float wor[12], bor[3];
    #pragma unroll
    for (int k = 0; k < 3; ++k) {
        int r = bid * 12 + wave * 3 + k;
        bor[k] = bout[r];
        #pragma unroll
        for (int q = 0; q < 4; ++q) wor[k * 4 + q] = Wout[r * 256 + lane + 64 * q];
    }

    for (int i = tid; i < 3072; i += TPB) xs[i] = x[i];
    __syncthreads();

    // ---- phase 1: pairs (single sweep, distances kept in registers) ----
    float c2[4];
    #pragma unroll
    for (int h = 0; h < 4; ++h) c2[h] = wsf[WS_A + h] * LOG2E;

    int gi = (bid * TPB + tid) * 16;       // 65536 threads * 16 = 1024^2 ordered pairs
    int i0 = gi >> 10, j0 = gi & 1023;     // 16 | 1024 -> row fixed per thread
    float xi0 = xs[3 * i0], xi1 = xs[3 * i0 + 1], xi2 = xs[3 * i0 + 2];
    float dreg[16];
    float tmax = -INFINITY, tmin = INFINITY;
    #pragma unroll
    for (int e = 0; e < 16; ++e) {
        int j = j0 + e;
        float dx = xi0 - xs[3 * j], dy = xi1 - xs[3 * j + 1], dz = xi2 - xs[3 * j + 2];
        float d = sqrtf(dx * dx + dy * dy + dz * dz);
        dreg[e] = d;
        if (j != i0) { tmax = fmaxf(tmax, d); tmin = fminf(tmin, d); }
    }
    for (int o = 32; o; o >>= 1) {
        tmax = fmaxf(tmax, __shfl_xor(tmax, o));
        tmin = fminf(tmin, __shfl_xor(tmin, o));
    }
    if (lane == 0) { sc[wave] = tmax; sc[8 + wave] = tmin; }
    __syncthreads();
    float bmax = fmaxf(fmaxf(sc[0], sc[1]), fmaxf(sc[2], sc[3]));
    float bmin = fminf(fminf(sc[8], sc[9]), fminf(sc[10], sc[11]));
    float m2[4];  // block-local max logit (exp2 domain); logits monotone in d
    #pragma unroll
    for (int h = 0; h < 4; ++h) m2[h] = (c2[h] >= 0.f) ? c2[h] * bmax : c2[h] * bmin;

    float se[4] = {0, 0, 0, 0}, sd[4] = {0, 0, 0, 0};
    #pragma unroll
    for (int e = 0; e < 16; ++e) {
        int j = j0 + e;
        if (j == i0) continue;
        float d = dreg[e];
        #pragma unroll
        for (int h = 0; h < 4; ++h) {
            float ee = exp2f(c2[h] * d - m2[h]);
            se[h] += ee;
            sd[h] += d * ee;
        }
    }
    for (int o = 32; o; o >>= 1) {
        #pragma unroll
        for (int h = 0; h < 4; ++h) { se[h] += __shfl_xor(se[h], o); sd[h] += __shfl_xor(sd[h], o); }
    }
    __syncthreads();
    if (lane == 0) {
        #pragma unroll
        for (int h = 0; h < 4; ++h) { sc[wave * 8 + h] = se[h]; sc[wave * 8 + 4 + h] = sd[h]; }
    }
    __syncthreads();
    if (tid < 4) st_coh(&wsf[WS_PART + tid * 256 + bid], m2[tid]);
    if (tid < 8) st_coh(&wsf[WS_PART + (4 + tid) * 256 + bid],
                        sc[tid] + sc[8 + tid] + sc[16 + tid] + sc[24 + tid]);

    // prefetch this block's W0 row while others finish phase 1
    float w0r[13];
    #pragma unroll
    for (int k = 0; k < 12; ++k) w0r[k] = W0[bid * 3137 + tid + k * 256];
    w0r[12] = (tid < 65) ? W0[bid * 3137 + 3072 + tid] : 0.f;

    grid_barrier(bar + 0 * BAR_REGION, bid);

    // ---- phase 2: LSE-merge 256 partials (redundant per block) + layer0 matvec ----
    float pm[4], pse[4], psd[4];
    #pragma unroll
    for (int h = 0; h < 4; ++h) {
        pm[h]  = ld_coh(&wsf[WS_PART + h * 256 + tid]);
        pse[h] = ld_coh(&wsf[WS_PART + (4 + h) * 256 + tid]);
        psd[h] = ld_coh(&wsf[WS_PART + (8 + h) * 256 + tid]);
    }
    float pmr[4] = {pm[0], pm[1], pm[2], pm[3]};
    for (int o = 32; o; o >>= 1) {
        #pragma unroll
        for (int h = 0; h < 4; ++h) pmr[h] = fmaxf(pmr[h], __shfl_xor(pmr[h], o));
    }
    if (lane == 0) {
        #pragma unroll
        for (int h = 0; h < 4; ++h) sc[wave * 4 + h] = pmr[h];
    }
    __syncthreads();
    float gm[4];
    #pragma unroll
    for (int h = 0; h < 4; ++h)
        gm[h] = fmaxf(fmaxf(sc[h], sc[4 + h]), fmaxf(sc[8 + h], sc[12 + h]));
    float s8[8];
    #pragma unroll
    for (int h = 0; h < 4; ++h) {
        float scl = exp2f(pm[h] - gm[h]);
        s8[h] = pse[h] * scl;
        s8[4 + h] = psd[h] * scl;
    }
    for (int o = 32; o; o >>= 1) {
        #pragma unroll
        for (int k = 0; k < 8; ++k) s8[k] += __shfl_xor(s8[k], o);
    }
    __syncthreads();
    if (lane == 0) {
        #pragma unroll
        for (int k = 0; k < 8; ++k) sc[wave * 8 + k] = s8[k];
    }
    __syncthreads();
    float s_tot = 0.f;
    #pragma unroll
    for (int h = 0; h < 4; ++h) {
        float seh = sc[h] + sc[8 + h] + sc[16 + h] + sc[24 + h];
        float sdh = sc[4 + h] + sc[12 + h] + sc[20 + h] + sc[28 + h];
        s_tot += sdh / seh;
    }

    // layer0: z0[bid] = W0[bid,:] . [x, s_tot*Wv+4bv, t] + b0[bid]
    float acc = 0.f;
    #pragma unroll
    for (int k = 0; k < 12; ++k) acc += w0r[k] * xs[tid + k * 256];
    float feat12 = (tid < 64) ? (s_tot * wvv + 4.0f * bvv) : ((tid == 64) ? t0 : 0.f);
    acc += w0r[12] * feat12;
    for (int o = 32; o; o >>= 1) acc += __shfl_xor(acc, o);
    __syncthreads();
    if (lane == 0) sc[wave] = acc;
    __syncthreads();
    if (tid == 0) st_coh(&wsf[WS_Z + bid], sc[0] + sc[1] + sc[2] + sc[3] + b0v);

    grid_barrier(bar + 1 * BAR_REGION, bid);

    // ---- hidden layers: thread t holds W[bid][t] and h[t] -> dot is a block reduce ----
    {
        float zv = ld_coh(&wsf[WS_Z + tid]);
        float ssum = block_sum_all(zv * zv, sc, lane, wave);
        float hv = gelu_fast(zv * rsqrtf(ssum * (1.f / 256.f) + EPS) * gg0);
        float a = w1 * hv;
        for (int o = 32; o; o >>= 1) a += __shfl_xor(a, o);
        __syncthreads();
        if (lane == 0) sc[wave] = a;
        __syncthreads();
        if (tid == 0) st_coh(&wsf[WS_Z + 256 + bid], sc[0] + sc[1] + sc[2] + sc[3] + bz1);
    }
    grid_barrier(bar + 2 * BAR_REGION, bid);
    {
        float zv = ld_coh(&wsf[WS_Z + 256 + tid]);
        float ssum = block_sum_all(zv * zv, sc, lane, wave);
        float hv = gelu_fast(zv * rsqrtf(ssum * (1.f / 256.f) + EPS) * gg1);
        float a = w2 * hv;
        for (int o = 32; o; o >>= 1) a += __shfl_xor(a, o);
        __syncthreads();
        if (lane == 0) sc[wave] = a;
        __syncthreads();
        if (tid == 0) st_coh(&wsf[WS_Z + 512 + bid], sc[0] + sc[1] + sc[2] + sc[3] + bz2);
    }
    grid_barrier(bar + 3 * BAR_REGION, bid);
    {
        float zv = ld_coh(&wsf[WS_Z + 512 + tid]);
        float ssum = block_sum_all(zv * zv, sc, lane, wave);
        float hv = gelu_fast(zv * rsqrtf(ssum * (1.f / 256.f) + EPS) * gg2);
        float a = w3 * hv;
        for (int o = 32; o; o >>= 1) a += __shfl_xor(a, o);
        __syncthreads();
        if (lane == 0) sc[wave] = a;
        __syncthreads();
        if (tid == 0) st_coh(&wsf[WS_Z + 768 + bid], sc[0] + sc[1] + sc[2] + sc[3] + bz3);
    }
    grid_barrier(bar + 4 * BAR_REGION, bid);

    // ---- output layer: 12 rows per block, 3 rows per wave (weights preloaded) ----
    {
        float zv = ld_coh(&wsf[WS_Z + 768 + tid]);
        float ssum = block_sum_all(zv * zv, sc, lane, wave);
        float hv = gelu_fast(zv * rsqrtf(ssum * (1.f / 256.f) + EPS) * gg3);
        hs[tid] = hv;
        __syncthreads();
        #pragma unroll
        for (int k = 0; k < 3; ++k) {
            float a = 0.f;
            #pragma unroll
            for (int q = 0; q < 4; ++q) a += wor[k * 4 + q] * hs[lane + 64 * q];
            for (int o = 32; o; o >>= 1) a += __shfl_xor(a, o);
            if (lane == 0) out[bid * 12 + wave * 3 + k] = a + bor[k];
        }
    }
}

extern "C" void kernel_launch(void* const* d_in, const int* in_sizes, int n_in,
                              void* d_out, int out_size, void* d_ws, size_t ws_size,
                              hipStream_t stream) {
    const float* x = (const float*)d_in[0];
    const float* t = (const float*)d_in[1];
    const float* Wk = (const float*)d_in[2];
    // d_in[3] = bk: cancels in softmax, unused
    const float* Wv = (const float*)d_in[4];
    const float* bv = (const float*)d_in[5];
    const float* Wq = (const float*)d_in[6];
    const float* bq = (const float*)d_in[7];
    const float* W0 = (const float*)d_in[8];
    const float* b0 = (const float*)d_in[9];
    const float* Wh = (const float*)d_in[10];
    const float* bh = (const float*)d_in[11];
    const float* Wout = (const float*)d_in[12];
    const float* bout = (const float*)d_in[13];
    const float* g = (const float*)d_in[14];
    float* out = (float*)d_out;
    float* wsf = (float*)d_ws;

    vf_init<<<1, 256, 0, stream>>>(t, Wq, bq, Wk, wsf);
    vf_fused<<<NB, TPB, 0, stream>>>(x, t, Wv, bv, W0, b0, Wh, bh, Wout, bout, g, out, wsf);
}